// Round 7
// baseline (46.389 us; speedup 1.0000x reference)
//
#include <hip/hip_runtime.h>

#define C_DIM 512
#define HID   256
#define B_DIM 8
#define L_DIM 196
#define BK    32               // K-step (phase 1)
#define MT    64               // l-tile (phase 1), 196 padded to 4 tiles of 64
#define NT    64               // h-tile (phase 1)
#define LPAD  68               // LDS row stride in floats (68: spreads banks)
#define NSTEP (C_DIM/BK)       // 16
#define ROWS  14               // i-rows per wave (phase 2)
#define LT    14
#define NJC   14               // j-chunks (phase 2)
#define JCL   (L_DIM/NJC)      // 14
#define PAIR_BLOCKS ((B_DIM*NJC*LT)/4)      // 392
#define P_ELEMS        (B_DIM*L_DIM*HID)
#define PARTIAL_ELEMS  (B_DIM*NJC*L_DIM)

// Phase 1 as a canonical tiled GEMM (fp32, vector ALU):
//   p[b,l,h] = sum_c f[b,c,l] * W[c,h]  (+ b1[h] folded into p1)
// Block = 64l x 64h tile, K=512 in 16 steps of BK=32, double-buffered LDS,
// reg-staged with early-issued global loads (T14 split). Grid = 256 = 1/CU.
// W traffic: 25 MB (vs 224 MB streaming) -> inner loop is LDS+VALU only.
__global__ __launch_bounds__(256) void gemm_p_kernel(
    const float* __restrict__ f1, const float* __restrict__ f2,
    const float* __restrict__ W1, const float* __restrict__ b1,
    float* __restrict__ p1, float* __restrict__ p2) {
  const int which = blockIdx.y;
  const int lt = blockIdx.x & 3;
  const int ht = (blockIdx.x >> 2) & 3;
  const int b  = blockIdx.x >> 4;              // 0..7
  const float* __restrict__ f = which ? f2 : f1;
  const float* __restrict__ W = W1 + which * C_DIM * HID;
  float* __restrict__ p = which ? p2 : p1;

  __shared__ float A_lds[2][BK][LPAD];         // 34.8 KB  (A = f-tile, [k][l])
  __shared__ float B_lds[2][BK][LPAD];         // 34.8 KB  (B = W-tile, [k][h])

  const int tid = threadIdx.x;
  // staging: thread covers rows kr0 and kr0+16, quad q (4 floats each)
  const int kr0 = tid >> 4;                    // 0..15
  const int kr1 = kr0 + 16;
  const int q   = tid & 15;
  int la = lt * MT + q * 4;
  if (la > 192) la = 192;                      // clamp: keep reads in-bounds (lt=3)
  const float* __restrict__ pA0 = f + (b * C_DIM + kr0) * L_DIM + la;
  const float* __restrict__ pA1 = f + (b * C_DIM + kr1) * L_DIM + la;
  const float* __restrict__ pB0 = W + kr0 * HID + ht * NT + q * 4;
  const float* __restrict__ pB1 = W + kr1 * HID + ht * NT + q * 4;

  // compute mapping: wave w -> 32x32 quadrant; lane -> 4l x 4h
  const int lane = tid & 63;
  const int w    = tid >> 6;
  const int qr = lane >> 3;                    // 0..7 l-quad
  const int qc = lane & 7;                     // 0..7 h-quad
  const int wl = (w & 1) * 32;
  const int wh = (w >> 1) * 32;

  float4 acc[4];
  #pragma unroll
  for (int i = 0; i < 4; ++i) acc[i] = make_float4(0.f, 0.f, 0.f, 0.f);

  // prologue: load step 0 into registers
  float4 sa0 = *(const float4*)pA0;
  float4 sa1 = *(const float4*)pA1;
  float4 sb0 = *(const float4*)pB0;
  float4 sb1 = *(const float4*)pB1;

  for (int t = 0; t < NSTEP; ++t) {
    const int cur = t & 1;
    // write staged regs to LDS (buf[cur] last read two steps ago -> safe)
    *(float4*)&A_lds[cur][kr0][q * 4] = sa0;
    *(float4*)&A_lds[cur][kr1][q * 4] = sa1;
    *(float4*)&B_lds[cur][kr0][q * 4] = sb0;
    *(float4*)&B_lds[cur][kr1][q * 4] = sb1;
    // issue next step's global loads EARLY (in flight across compute)
    if (t + 1 < NSTEP) {
      const int ko = (t + 1) * BK;
      sa0 = *(const float4*)(pA0 + ko * L_DIM);
      sa1 = *(const float4*)(pA1 + ko * L_DIM);
      sb0 = *(const float4*)(pB0 + ko * HID);
      sb1 = *(const float4*)(pB1 + ko * HID);
    }
    __syncthreads();                           // writes visible to all waves
    #pragma unroll
    for (int k = 0; k < BK; ++k) {
      const float4 av = *(const float4*)&A_lds[cur][k][wl + qr * 4];  // broadcast
      const float4 bv = *(const float4*)&B_lds[cur][k][wh + qc * 4];  // broadcast
      acc[0].x = fmaf(av.x, bv.x, acc[0].x);
      acc[0].y = fmaf(av.x, bv.y, acc[0].y);
      acc[0].z = fmaf(av.x, bv.z, acc[0].z);
      acc[0].w = fmaf(av.x, bv.w, acc[0].w);
      acc[1].x = fmaf(av.y, bv.x, acc[1].x);
      acc[1].y = fmaf(av.y, bv.y, acc[1].y);
      acc[1].z = fmaf(av.y, bv.z, acc[1].z);
      acc[1].w = fmaf(av.y, bv.w, acc[1].w);
      acc[2].x = fmaf(av.z, bv.x, acc[2].x);
      acc[2].y = fmaf(av.z, bv.y, acc[2].y);
      acc[2].z = fmaf(av.z, bv.z, acc[2].z);
      acc[2].w = fmaf(av.z, bv.w, acc[2].w);
      acc[3].x = fmaf(av.w, bv.x, acc[3].x);
      acc[3].y = fmaf(av.w, bv.y, acc[3].y);
      acc[3].z = fmaf(av.w, bv.z, acc[3].z);
      acc[3].w = fmaf(av.w, bv.w, acc[3].w);
    }
    __syncthreads();                           // all reads of buf[cur] done
  }

  // epilogue: bias (p1 only) + masked coalesced store
  const int l_base = lt * MT + wl + qr * 4;
  const int h0 = ht * NT + wh + qc * 4;
  float4 bias = make_float4(0.f, 0.f, 0.f, 0.f);
  if (!which) bias = *(const float4*)(b1 + h0);
  #pragma unroll
  for (int i = 0; i < 4; ++i) {
    const int l = l_base + i;
    if (l < L_DIM) {
      const float4 ai = acc[i];
      float4 r;
      r.x = ai.x + bias.x;
      r.y = ai.y + bias.y;
      r.z = ai.z + bias.z;
      r.w = ai.w + bias.w;
      *(float4*)(p + (b * L_DIM + l) * HID + h0) = r;
    }
  }
}

// Phase 2 (r6 exact): wave = 14 i-rows x one 14-j chunk.
// partial[b,jc,i] = sum_{j in chunk jc} relu(p1[b,i,:]+p2[b,j,:]).W2
__global__ __launch_bounds__(256) void pair_kernel(
    const float* __restrict__ p1, const float* __restrict__ p2,
    const float* __restrict__ W2, float* __restrict__ partial) {
  const int lane = threadIdx.x & 63;
  const int wid  = blockIdx.x * 4 + (threadIdx.x >> 6);   // 0..1567
  const int b  = wid / (NJC * LT);
  const int r  = wid % (NJC * LT);
  const int jc = r / LT;                                  // 0..13
  const int wi = r % LT;                                  // 0..13

  const float4 w = *(const float4*)(W2 + lane * 4);
  const float* __restrict__ p1b = p1 + (b * L_DIM) * HID + lane * 4;

  float4 a[ROWS];
  #pragma unroll
  for (int k = 0; k < ROWS; ++k)
    a[k] = *(const float4*)(p1b + (wi + k * LT) * HID);   // i = wi + k*14

  float s[ROWS];
  #pragma unroll
  for (int k = 0; k < ROWS; ++k) s[k] = 0.0f;

  const float4* __restrict__ vp =
      (const float4*)(p2 + (b * L_DIM + jc * JCL) * HID) + lane;

#define PAIR_BODY(vv)                                          \
  {                                                            \
    _Pragma("unroll")                                          \
    for (int k = 0; k < ROWS; ++k) {                           \
      s[k] = fmaf(fmaxf(a[k].x + (vv).x, 0.f), w.x, s[k]);     \
      s[k] = fmaf(fmaxf(a[k].y + (vv).y, 0.f), w.y, s[k]);     \
      s[k] = fmaf(fmaxf(a[k].z + (vv).z, 0.f), w.z, s[k]);     \
      s[k] = fmaf(fmaxf(a[k].w + (vv).w, 0.f), w.w, s[k]);     \
    }                                                          \
  }

  float4 v = vp[0];
  #pragma unroll
  for (int j = 0; j < JCL - 1; ++j) {           // branch-free preload pipeline
    float4 vn = vp[(j + 1) * (HID / 4)];
    PAIR_BODY(v);
    v = vn;
  }
  PAIR_BODY(v);
#undef PAIR_BODY

  #pragma unroll
  for (int off = 32; off > 0; off >>= 1) {
    #pragma unroll
    for (int k = 0; k < ROWS; ++k) s[k] += __shfl_down(s[k], off);
  }
  if (lane == 0) {
    float* pp = partial + (b * NJC + jc) * L_DIM;
    #pragma unroll
    for (int k = 0; k < ROWS; ++k) pp[wi + k * LT] = s[k];
  }
}

// Phase 3 (r6 exact): out[b] = sum over NJC*L partials + L*L*b2
__global__ __launch_bounds__(256) void reduce_kernel(
    const float* __restrict__ partial, const float* __restrict__ b2,
    float* __restrict__ out) {
  const int b = blockIdx.x;
  const int t = threadIdx.x;
  float acc = 0.0f;
  for (int idx = t; idx < NJC * L_DIM; idx += 256)
    acc += partial[b * NJC * L_DIM + idx];
  #pragma unroll
  for (int off = 32; off > 0; off >>= 1) acc += __shfl_down(acc, off);
  __shared__ float sred[4];
  if ((t & 63) == 0) sred[t >> 6] = acc;
  __syncthreads();
  if (t == 0)
    out[b] = sred[0] + sred[1] + sred[2] + sred[3]
           + (float)(L_DIM * L_DIM) * b2[0];
}

extern "C" void kernel_launch(void* const* d_in, const int* in_sizes, int n_in,
                              void* d_out, int out_size, void* d_ws, size_t ws_size,
                              hipStream_t stream) {
  const float* f1 = (const float*)d_in[0];   // [B, C, 14, 14]
  const float* f2 = (const float*)d_in[1];
  const float* W1 = (const float*)d_in[2];   // [2C, HID]
  const float* b1 = (const float*)d_in[3];   // [HID]
  const float* W2 = (const float*)d_in[4];   // [HID, 1]
  const float* b2 = (const float*)d_in[5];   // [1]
  float* out = (float*)d_out;                // [B, 1]

  float* p1      = (float*)d_ws;
  float* p2      = p1 + P_ELEMS;
  float* partial = p2 + P_ELEMS;

  dim3 g1(128, 2);                           // (lt:4 | ht:4 | b:8) x side
  gemm_p_kernel<<<g1, 256, 0, stream>>>(f1, f2, W1, b1, p1, p2);

  pair_kernel<<<PAIR_BLOCKS, 256, 0, stream>>>(p1, p2, W2, partial);

  reduce_kernel<<<B_DIM, 256, 0, stream>>>(partial, b2, out);
}

// Round 8
// 34.438 us; speedup vs baseline: 1.3470x; 1.3470x over previous
//
#include <hip/hip_runtime.h>

typedef __attribute__((ext_vector_type(8))) short bf16x8;
typedef __attribute__((ext_vector_type(4))) float f32x4;

#define C_DIM 512
#define HID   256
#define B_DIM 8
#define L_DIM 196
#define MROWS (B_DIM*L_DIM)     // 1568 = 49*32, exact
#define MT    32                // rows per block (2 m-frags of 16)
#define NLT   (MROWS/MT)        // 49 m-tiles
#define KSTEP (C_DIM/32)        // 16 k-steps of 32
#define ROWS  14                // i-rows per wave (phase 2)
#define LT    14
#define NJC   14                // j-chunks (phase 2)
#define JCL   (L_DIM/NJC)       // 14
#define PAIR_BLOCKS ((B_DIM*NJC*LT)/4)      // 392
#define P_ELEMS        (B_DIM*L_DIM*HID)
#define PARTIAL_ELEMS  (B_DIM*NJC*L_DIM)

// f32 -> bf16 bits, round-to-nearest (ties up): 2 VALU ops
__device__ __forceinline__ short bf16r(float x) {
  unsigned u = __builtin_bit_cast(unsigned, x);
  return (short)((u + 0x8000u) >> 16);
}

// Phase 1 via MFMA (bf16 inputs, fp32 accumulate), on-the-fly conversion:
//   p[r,h] = sum_c f[b(r),c,l(r)] * W[c,h]   (+ b1[h] for side 0)
// One wave per block: 32 rows x 64 h (2 m-frags x 4 n-frags, 16x16x32).
// A-frag: lane holds rows (lane&15), k-chunk (lane>>4)*8+i  (same per-lane
// k-permutation for A and B -> any k-mapping uncertainty cancels in the dot).
// Grid = 49 m-tiles x 4 h-tiles x 2 sides = 392 blocks of 64 threads.
__global__ __launch_bounds__(64) void gemm_p_mfma(
    const float* __restrict__ f1, const float* __restrict__ f2,
    const float* __restrict__ W1, const float* __restrict__ b1,
    float* __restrict__ p1, float* __restrict__ p2) {
  const int side = blockIdx.y;
  const int lt = blockIdx.x % NLT;              // m-tile
  const int ht = blockIdx.x / NLT;              // 0..3 (64 h each)
  const float* __restrict__ f = side ? f2 : f1;
  const float* __restrict__ W = W1 + side * C_DIM * HID;
  float* __restrict__ p = side ? p2 : p1;

  const int lane = threadIdx.x;
  const int g    = lane >> 4;                   // k-chunk group 0..3
  const int mcol = lane & 15;

  // per-lane A row bases: r -> (b, l); A[r][k] = f[(b*C + k)*L + l]
  int aoff[2];
  #pragma unroll
  for (int mi = 0; mi < 2; ++mi) {
    const int r = lt * MT + mi * 16 + mcol;     // < 1568 always
    const int b = r / L_DIM;
    const int l = r - b * L_DIM;
    aoff[mi] = (b * C_DIM) * L_DIM + l;
  }
  const int h0 = ht * 64 + mcol;                // B col base (+ni*16)

  f32x4 acc[2][4];
  #pragma unroll
  for (int mi = 0; mi < 2; ++mi)
    #pragma unroll
    for (int ni = 0; ni < 4; ++ni)
      acc[mi][ni] = (f32x4){0.f, 0.f, 0.f, 0.f};

  for (int ks = 0; ks < KSTEP; ++ks) {
    const int k0 = ks * 32 + g * 8;             // this lane's 8 k's
    bf16x8 afr[2], bfr[4];
    #pragma unroll
    for (int mi = 0; mi < 2; ++mi) {
      const float* __restrict__ pa = f + aoff[mi] + k0 * L_DIM;
      #pragma unroll
      for (int i = 0; i < 8; ++i) afr[mi][i] = bf16r(pa[i * L_DIM]);
    }
    #pragma unroll
    for (int ni = 0; ni < 4; ++ni) {
      const float* __restrict__ pb = W + k0 * HID + h0 + ni * 16;
      #pragma unroll
      for (int i = 0; i < 8; ++i) bfr[ni][i] = bf16r(pb[i * HID]);
    }
    #pragma unroll
    for (int mi = 0; mi < 2; ++mi)
      #pragma unroll
      for (int ni = 0; ni < 4; ++ni)
        acc[mi][ni] = __builtin_amdgcn_mfma_f32_16x16x32_bf16(
            afr[mi], bfr[ni], acc[mi][ni], 0, 0, 0);
  }

  // C/D layout (verified): col = lane&15, row = (lane>>4)*4 + reg
  #pragma unroll
  for (int mi = 0; mi < 2; ++mi) {
    const int r0 = lt * MT + mi * 16 + g * 4;
    #pragma unroll
    for (int ni = 0; ni < 4; ++ni) {
      const int h = h0 + ni * 16;
      const float bias = side ? 0.0f : b1[h];   // fold b1 into p1 only
      #pragma unroll
      for (int reg = 0; reg < 4; ++reg)
        p[(r0 + reg) * HID + h] = acc[mi][ni][reg] + bias;
    }
  }
}

// Phase 2 (r6 exact): wave = 14 i-rows x one 14-j chunk.
// partial[b,jc,i] = sum_{j in chunk jc} relu(p1[b,i,:]+p2[b,j,:]).W2
__global__ __launch_bounds__(256) void pair_kernel(
    const float* __restrict__ p1, const float* __restrict__ p2,
    const float* __restrict__ W2, float* __restrict__ partial) {
  const int lane = threadIdx.x & 63;
  const int wid  = blockIdx.x * 4 + (threadIdx.x >> 6);   // 0..1567
  const int b  = wid / (NJC * LT);
  const int r  = wid % (NJC * LT);
  const int jc = r / LT;                                  // 0..13
  const int wi = r % LT;                                  // 0..13

  const float4 w = *(const float4*)(W2 + lane * 4);
  const float* __restrict__ p1b = p1 + (b * L_DIM) * HID + lane * 4;

  float4 a[ROWS];
  #pragma unroll
  for (int k = 0; k < ROWS; ++k)
    a[k] = *(const float4*)(p1b + (wi + k * LT) * HID);   // i = wi + k*14

  float s[ROWS];
  #pragma unroll
  for (int k = 0; k < ROWS; ++k) s[k] = 0.0f;

  const float4* __restrict__ vp =
      (const float4*)(p2 + (b * L_DIM + jc * JCL) * HID) + lane;

#define PAIR_BODY(vv)                                          \
  {                                                            \
    _Pragma("unroll")                                          \
    for (int k = 0; k < ROWS; ++k) {                           \
      s[k] = fmaf(fmaxf(a[k].x + (vv).x, 0.f), w.x, s[k]);     \
      s[k] = fmaf(fmaxf(a[k].y + (vv).y, 0.f), w.y, s[k]);     \
      s[k] = fmaf(fmaxf(a[k].z + (vv).z, 0.f), w.z, s[k]);     \
      s[k] = fmaf(fmaxf(a[k].w + (vv).w, 0.f), w.w, s[k]);     \
    }                                                          \
  }

  float4 v = vp[0];
  #pragma unroll
  for (int j = 0; j < JCL - 1; ++j) {           // branch-free preload pipeline
    float4 vn = vp[(j + 1) * (HID / 4)];
    PAIR_BODY(v);
    v = vn;
  }
  PAIR_BODY(v);
#undef PAIR_BODY

  #pragma unroll
  for (int off = 32; off > 0; off >>= 1) {
    #pragma unroll
    for (int k = 0; k < ROWS; ++k) s[k] += __shfl_down(s[k], off);
  }
  if (lane == 0) {
    float* pp = partial + (b * NJC + jc) * L_DIM;
    #pragma unroll
    for (int k = 0; k < ROWS; ++k) pp[wi + k * LT] = s[k];
  }
}

// Phase 3 (r6 exact): out[b] = sum over NJC*L partials + L*L*b2
__global__ __launch_bounds__(256) void reduce_kernel(
    const float* __restrict__ partial, const float* __restrict__ b2,
    float* __restrict__ out) {
  const int b = blockIdx.x;
  const int t = threadIdx.x;
  float acc = 0.0f;
  for (int idx = t; idx < NJC * L_DIM; idx += 256)
    acc += partial[b * NJC * L_DIM + idx];
  #pragma unroll
  for (int off = 32; off > 0; off >>= 1) acc += __shfl_down(acc, off);
  __shared__ float sred[4];
  if ((t & 63) == 0) sred[t >> 6] = acc;
  __syncthreads();
  if (t == 0)
    out[b] = sred[0] + sred[1] + sred[2] + sred[3]
           + (float)(L_DIM * L_DIM) * b2[0];
}

extern "C" void kernel_launch(void* const* d_in, const int* in_sizes, int n_in,
                              void* d_out, int out_size, void* d_ws, size_t ws_size,
                              hipStream_t stream) {
  const float* f1 = (const float*)d_in[0];   // [B, C, 14, 14]
  const float* f2 = (const float*)d_in[1];
  const float* W1 = (const float*)d_in[2];   // [2C, HID]
  const float* b1 = (const float*)d_in[3];   // [HID]
  const float* W2 = (const float*)d_in[4];   // [HID, 1]
  const float* b2 = (const float*)d_in[5];   // [1]
  float* out = (float*)d_out;                // [B, 1]

  float* p1      = (float*)d_ws;
  float* p2      = p1 + P_ELEMS;
  float* partial = p2 + P_ELEMS;

  dim3 g1(NLT * 4, 2);                       // (49 m-tiles x 4 h-tiles, 2 sides)
  gemm_p_mfma<<<g1, 64, 0, stream>>>(f1, f2, W1, b1, p1, p2);

  pair_kernel<<<PAIR_BLOCKS, 256, 0, stream>>>(p1, p2, W2, partial);

  reduce_kernel<<<B_DIM, 256, 0, stream>>>(partial, b2, out);
}